// Round 10
// baseline (146.806 us; speedup 1.0000x reference)
//
#include <hip/hip_runtime.h>
#include <math.h>

#define N_PTS     131072
#define G_NUMS    30
#define G_SIZE    100
#define PT_STRIDE (N_PTS / G_NUMS)   // 4369
#define TPB       1024
#define NWAVES    (TPB / 64)         // 16
#define BINS      4096
#define JB        (BINS / TPB)       // 4 bins per thread
#define SHIFT     20
#define SAMPLE_GRPS 1024             // fallback sample: first 4096 pts
#define RANK_CUT  32                 // fallback rank
#define CAP       3072               // survivor capacity
#define TIE_CAP   64
// register-bisection tau: 2048-pt sample, rank-12 => E[survivors] ~ 770
#define SMP_N     2048
#define SMP_PL    (SMP_N / 64)       // 32 sample d^2 per lane
#define SMP_CUT   12
#define SMP_ITERS 13                 // bracket within ~2% of target d^2

struct KSmem {
    union {
        unsigned hist[BINS];         // 16 KB
        struct {                     // finalize overlay (last block only)
            float gm[256][3];
            float dir[256][3];
            float pe[NWAVES];
            float ps[NWAVES];
        } fin;
    };
    unsigned wsum[NWAVES];
    unsigned T;
    int ns, nd, nt;
    unsigned u[CAP];
    int idx[CAP];
    float px[CAP], py[CAP], pz[CAP]; // sample stage, then survivor coords
    int sel[G_SIZE];                 // positions into survivor arrays
    unsigned tu[TIE_CAP];
    int ti[TIE_CAP];                 // positions
    float acc[3], cov[6], q[3];
    unsigned tau0, maxu, r1;
    float delta2;
};

__device__ __forceinline__ float dist2f(float px, float py, float pz,
                                        float qx, float qy, float qz) {
    float dx = px - qx, dy = py - qy, dz = pz - qz;
    return fmaf(dx, dx, fmaf(dy, dy, dz * dz));
}

// Find smallest bin T such that cumulative count through T >= rank.
__device__ __forceinline__ unsigned find_bin(KSmem& sm, unsigned rank,
                                             int tid, int lane, int wid) {
    unsigned hv[JB], csum = 0;
#pragma unroll
    for (int j = 0; j < JB; j++) { hv[j] = sm.hist[tid * JB + j]; csum += hv[j]; }
    unsigned inc = csum;
#pragma unroll
    for (int off = 1; off < 64; off <<= 1) {
        unsigned n = __shfl_up(inc, off);
        if (lane >= off) inc += n;
    }
    __syncthreads();                  // protect wsum reuse across calls
    if (lane == 63) sm.wsum[wid] = inc;
    __syncthreads();
    unsigned base = 0;
    for (int w = 0; w < wid; w++) base += sm.wsum[w];
    unsigned c = base + inc - csum;   // exclusive prefix before this thread's chunk
#pragma unroll
    for (int j = 0; j < JB; j++) {
        if (c < rank && c + hv[j] >= rank) sm.T = (unsigned)(tid * JB + j);
        c += hv[j];
    }
    __syncthreads();
    return sm.T;
}

// Exact top-100 select over sm.u[0..min(ns,CAP)) -> sm.sel positions.
// ubound: known upper bound (bits) on all u values (sets histogram shift).
// Requires sm.hist zeroed and sm.nd/nt zeroed on entry.
__device__ void fine_select(KSmem& sm, unsigned ubound, int tid, int lane, int wid) {
    int S = sm.ns; if (S > CAP) S = CAP;
    unsigned hb = 32u - (unsigned)__clz(ubound | 1u);
    unsigned s2 = hb > 12u ? hb - 12u : 0u;
    for (int i = tid; i < S; i += TPB) {
        unsigned bin = sm.u[i] >> s2; if (bin > BINS - 1u) bin = BINS - 1u;
        atomicAdd(&sm.hist[bin], 1u);
    }
    __syncthreads();
    unsigned T2 = find_bin(sm, G_SIZE, tid, lane, wid);
    for (int i = tid; i < S; i += TPB) {
        unsigned uu = sm.u[i];
        unsigned bin = uu >> s2; if (bin > BINS - 1u) bin = BINS - 1u;
        if (bin < T2) {
            int p = atomicAdd(&sm.nd, 1);
            if (p < G_SIZE) sm.sel[p] = i;
        } else if (bin == T2) {
            int p = atomicAdd(&sm.nt, 1);
            if (p < TIE_CAP) { sm.tu[p] = uu; sm.ti[p] = i; }
        }
    }
    __syncthreads();
    if (tid == 0) {
        int nd = sm.nd; if (nd > G_SIZE) nd = G_SIZE;
        int need = G_SIZE - nd;
        int ec = sm.nt; if (ec > TIE_CAP) ec = TIE_CAP;
        for (int a = 0; a < need && a < ec; ++a) {
            int best = a;
            for (int j = a + 1; j < ec; ++j)
                if (sm.tu[j] < sm.tu[best] ||
                    (sm.tu[j] == sm.tu[best] && sm.idx[sm.ti[j]] < sm.idx[sm.ti[best]])) best = j;
            unsigned tub = sm.tu[best]; sm.tu[best] = sm.tu[a]; sm.tu[a] = tub;
            int tib = sm.ti[best]; sm.ti[best] = sm.ti[a]; sm.ti[a] = tib;
            sm.sel[nd + a] = sm.ti[a];
        }
    }
    __syncthreads();
}

// Exact AoS distance+filter+stash for one float4-group (4 points).
__device__ __forceinline__ void push4(KSmem& sm, const float4& xv, const float4& yv,
                                      const float4& zv, int i, unsigned tau,
                                      float qx, float qy, float qz) {
    unsigned u0 = __float_as_uint(dist2f(xv.x, yv.x, zv.x, qx, qy, qz));
    unsigned u1 = __float_as_uint(dist2f(xv.y, yv.y, zv.y, qx, qy, qz));
    unsigned u2 = __float_as_uint(dist2f(xv.z, yv.z, zv.z, qx, qy, qz));
    unsigned u3 = __float_as_uint(dist2f(xv.w, yv.w, zv.w, qx, qy, qz));
    int i0 = i * 4;
    if (u0 < tau) { int p = atomicAdd(&sm.ns, 1); if (p < CAP) { sm.u[p] = u0; sm.idx[p] = i0;     sm.px[p] = xv.x; sm.py[p] = yv.x; sm.pz[p] = zv.x; } }
    if (u1 < tau) { int p = atomicAdd(&sm.ns, 1); if (p < CAP) { sm.u[p] = u1; sm.idx[p] = i0 + 1; sm.px[p] = xv.y; sm.py[p] = yv.y; sm.pz[p] = zv.y; } }
    if (u2 < tau) { int p = atomicAdd(&sm.ns, 1); if (p < CAP) { sm.u[p] = u2; sm.idx[p] = i0 + 2; sm.px[p] = xv.z; sm.py[p] = yv.z; sm.pz[p] = zv.z; } }
    if (u3 < tau) { int p = atomicAdd(&sm.ns, 1); if (p < CAP) { sm.u[p] = u3; sm.idx[p] = i0 + 3; sm.px[p] = xv.w; sm.py[p] = yv.w; sm.pz[p] = zv.w; } }
}

// Exact AoS filter pass. Resets ns; fills u/idx/coords with d^2 < tau.
__device__ void filter_exact(const float4* __restrict__ P4, KSmem& sm, unsigned tau,
                             float qx, float qy, float qz, int tid) {
    if (tid == 0) sm.ns = 0;
    __syncthreads();
#pragma unroll 4
    for (int grp = tid; grp < N_PTS / 4; grp += TPB) {
        float4 f0 = P4[3 * grp + 0];
        float4 f1 = P4[3 * grp + 1];
        float4 f2 = P4[3 * grp + 2];
        float4 xv = make_float4(f0.x, f0.w, f1.z, f2.y);
        float4 yv = make_float4(f0.y, f1.x, f1.w, f2.z);
        float4 zv = make_float4(f0.z, f1.y, f2.x, f2.w);
        push4(sm, xv, yv, zv, grp, tau, qx, qy, qz);
    }
    __syncthreads();
}

// Fallback: histogram-sample tau (round-5 proven). Leaves hist zeroed.
__device__ unsigned sample_tau(const float4* __restrict__ P4, KSmem& sm,
                               float qx, float qy, float qz,
                               int tid, int lane, int wid) {
    for (int j = tid; j < BINS; j += TPB) sm.hist[j] = 0u;
    if (tid == 0) { sm.ns = 0; sm.nd = 0; sm.nt = 0; sm.T = 0u; }
    __syncthreads();
    for (int grp = tid; grp < SAMPLE_GRPS; grp += TPB) {
        float4 f0 = P4[3 * grp + 0];
        float4 f1 = P4[3 * grp + 1];
        float4 f2 = P4[3 * grp + 2];
        atomicAdd(&sm.hist[__float_as_uint(dist2f(f0.x, f0.y, f0.z, qx, qy, qz)) >> SHIFT], 1u);
        atomicAdd(&sm.hist[__float_as_uint(dist2f(f0.w, f1.x, f1.y, qx, qy, qz)) >> SHIFT], 1u);
        atomicAdd(&sm.hist[__float_as_uint(dist2f(f1.z, f1.w, f2.x, qx, qy, qz)) >> SHIFT], 1u);
        atomicAdd(&sm.hist[__float_as_uint(dist2f(f2.y, f2.z, f2.w, qx, qy, qz)) >> SHIFT], 1u);
    }
    __syncthreads();
    unsigned Tc = find_bin(sm, RANK_CUT, tid, lane, wid);
    unsigned tau = (Tc >= BINS - 1) ? 0xFFFFFFFFu : ((Tc + 1) << SHIFT);
    for (int j = tid; j < BINS; j += TPB) sm.hist[j] = 0u;   // re-zero for fine pass
    __syncthreads();
    return tau;
}

// Fallback exact 100-NN (round-5/9 proven path).
__device__ void knn_exact(const float4* __restrict__ P4, KSmem& sm,
                          float qx, float qy, float qz,
                          int tid, int lane, int wid, bool save_tau) {
    unsigned tau = sample_tau(P4, sm, qx, qy, qz, tid, lane, wid);
    if (save_tau && tid == 0) sm.tau0 = tau;
    filter_exact(P4, sm, tau, qx, qy, qz, tid);
    fine_select(sm, tau, tid, lane, wid);
}

// ---- 3x3 symmetric eigensolve (Jacobi, double) ----
__device__ void eig3(const float cf[6], double lam_out[3], double dir_out[3]) {
    double a[3][3], v[3][3];
    a[0][0] = cf[0]; a[0][1] = cf[1]; a[0][2] = cf[2];
    a[1][0] = cf[1]; a[1][1] = cf[3]; a[1][2] = cf[4];
    a[2][0] = cf[2]; a[2][1] = cf[4]; a[2][2] = cf[5];
    for (int i = 0; i < 3; i++)
        for (int j = 0; j < 3; j++) v[i][j] = (i == j) ? 1.0 : 0.0;
    for (int sweep = 0; sweep < 12; sweep++) {
        double off = a[0][1] * a[0][1] + a[0][2] * a[0][2] + a[1][2] * a[1][2];
        if (off == 0.0) break;
        for (int p = 0; p < 2; p++) {
            for (int q = p + 1; q < 3; q++) {
                double apq = a[p][q];
                if (apq == 0.0) continue;
                double app = a[p][p], aqq = a[q][q];
                double theta = (aqq - app) / (2.0 * apq);
                double t = (theta >= 0.0 ? 1.0 : -1.0) /
                           (fabs(theta) + sqrt(theta * theta + 1.0));
                double c = 1.0 / sqrt(t * t + 1.0);
                double s = t * c;
                a[p][p] = app - t * apq;
                a[q][q] = aqq + t * apq;
                a[p][q] = 0.0; a[q][p] = 0.0;
                for (int r = 0; r < 3; r++) {
                    if (r == p || r == q) continue;
                    double arp = a[r][p], arq = a[r][q];
                    a[r][p] = c * arp - s * arq; a[p][r] = a[r][p];
                    a[r][q] = s * arp + c * arq; a[q][r] = a[r][q];
                }
                for (int r = 0; r < 3; r++) {
                    double vrp = v[r][p], vrq = v[r][q];
                    v[r][p] = c * vrp - s * vrq;
                    v[r][q] = s * vrp + c * vrq;
                }
            }
        }
    }
    double l0 = a[0][0], l1 = a[1][1], l2 = a[2][2];
    int i0 = 0, i1 = 1, i2 = 2;
    if (l0 > l1) { double t = l0; l0 = l1; l1 = t; int ti = i0; i0 = i1; i1 = ti; }
    if (l1 > l2) { double t = l1; l1 = l2; l2 = t; int ti = i1; i1 = i2; i2 = ti; }
    if (l0 > l1) { double t = l0; l0 = l1; l1 = t; int ti = i0; i0 = i1; i1 = ti; }
    lam_out[0] = l0; lam_out[1] = l1; lam_out[2] = l2;
    dir_out[0] = v[0][i2]; dir_out[1] = v[1][i2]; dir_out[2] = v[2][i2];
}

// One block per (batch, group). Phase 0: register-bisection tau (2048-pt
// sample in LDS, all waves redundantly bisect -- deterministic, no atomics)
// -> exact filter -> hist select. Phase 1: certified survivor re-rank.
// Any anomaly -> round-5-proven exact path. No mid-kernel cross-block sync;
// single release-only election; ONE acquire in ONE block (rounds 2/8 lesson).
__global__ __launch_bounds__(TPB)
void fused_knn_kernel(const float* __restrict__ pts,
                      float* __restrict__ gmeans, float* __restrict__ covs,
                      float* __restrict__ out,
                      unsigned* __restrict__ syncw,   // [0] = elect
                      int B, int nblk) {
    __shared__ KSmem sm;
    __shared__ int s_fastok;
    __shared__ int s_last;

    const int blk = blockIdx.x;
    const int b = blk % B;           // batch-per-XCD swizzle (L2 locality)
    const int g = blk / B;
    const int gi = b * G_NUMS + g;   // b-major for finalize
    const float* __restrict__ P = pts + (size_t)b * (N_PTS * 3);
    const float4* __restrict__ P4 = (const float4*)P;
    const int tid = threadIdx.x;
    const int lane = tid & 63, wid = tid >> 6;

    // ---- init + stage 2048-pt sample as SoA into survivor arrays ----
    if (tid == 0) {
        const float* qp = P + (size_t)g * PT_STRIDE * 3;
        sm.q[0] = qp[0]; sm.q[1] = qp[1]; sm.q[2] = qp[2];
        sm.ns = 0; sm.nd = 0; sm.nt = 0; sm.T = 0u;
        s_last = 0;
    }
    if (tid < 3) sm.acc[tid] = 0.f;
    if (tid < 6) sm.cov[tid] = 0.f;
    for (int j = tid; j < BINS; j += TPB) sm.hist[j] = 0u;
    for (int t = tid; t < SMP_N / 4; t += TPB) {     // 512 groups
        float4 f0 = P4[3 * t + 0];
        float4 f1 = P4[3 * t + 1];
        float4 f2 = P4[3 * t + 2];
        sm.px[4 * t + 0] = f0.x; sm.px[4 * t + 1] = f0.w;
        sm.px[4 * t + 2] = f1.z; sm.px[4 * t + 3] = f2.y;
        sm.py[4 * t + 0] = f0.y; sm.py[4 * t + 1] = f1.x;
        sm.py[4 * t + 2] = f1.w; sm.py[4 * t + 3] = f2.z;
        sm.pz[4 * t + 0] = f0.z; sm.pz[4 * t + 1] = f1.y;
        sm.pz[4 * t + 2] = f2.x; sm.pz[4 * t + 3] = f2.w;
    }
    __syncthreads();
    const float qx = sm.q[0], qy = sm.q[1], qz = sm.q[2];

    // ---- register-bisection tau (every wave computes the identical value:
    //      same inputs, same op order -> deterministic; no LDS atomics) ----
    unsigned tau;
    {
        unsigned du[SMP_PL];
#pragma unroll
        for (int k = 0; k < SMP_PL; ++k) {
            int p = lane + 64 * k;                  // lane-consecutive: conflict-free
            du[k] = __float_as_uint(dist2f(sm.px[p], sm.py[p], sm.pz[p], qx, qy, qz));
        }
        unsigned lo = 0u, hi = 0x7F800000u;         // count(<lo)<CUT<=count(<hi)
        for (int it = 0; it < SMP_ITERS; ++it) {
            unsigned mid = (lo + hi) >> 1;
            int cnt = 0;
#pragma unroll
            for (int k = 0; k < SMP_PL; ++k) cnt += (du[k] < mid) ? 1 : 0;
#pragma unroll
            for (int off = 1; off < 64; off <<= 1) cnt += __shfl_xor(cnt, off);
            if (cnt >= SMP_CUT) hi = mid; else lo = mid;   // uniform branch
        }
        tau = hi;                                   // upper bracket of rank-CUT stat
    }
    __syncthreads();                                // all waves done reading sample
    if (tid == 0) sm.tau0 = tau;

    // ---- phase 0: exact filter + exact select ----
    filter_exact(P4, sm, tau, qx, qy, qz, tid);
    int S0 = sm.ns;
    bool anomaly = (S0 < G_SIZE) || (S0 > CAP);
    if (anomaly) {
        // pathological tau (prob ~1e-5): round-5-proven exact path
        knn_exact(P4, sm, qx, qy, qz, tid, lane, wid, true);
    } else {
        fine_select(sm, tau, tid, lane, wid);
    }

    if (tid < G_SIZE) {
        int p = sm.sel[tid];
        atomicAdd(&sm.acc[0], sm.px[p]);
        atomicAdd(&sm.acc[1], sm.py[p]);
        atomicAdd(&sm.acc[2], sm.pz[p]);
    }
    __syncthreads();
    S0 = sm.ns;                      // raw survivor count of the FINAL phase-0 filter
    if (tid == 0) {
        float mx = sm.acc[0] * (1.0f / G_SIZE);
        float my = sm.acc[1] * (1.0f / G_SIZE);
        float mz = sm.acc[2] * (1.0f / G_SIZE);
        gmeans[(size_t)gi * 3 + 0] = mx;
        gmeans[(size_t)gi * 3 + 1] = my;
        gmeans[(size_t)gi * 3 + 2] = mz;
        float dx = mx - qx, dy = my - qy, dz = mz - qz;
        sm.delta2 = fmaf(dx, dx, fmaf(dy, dy, dz * dz));
        sm.q[0] = mx; sm.q[1] = my; sm.q[2] = mz;
        sm.acc[0] = 0.f; sm.acc[1] = 0.f; sm.acc[2] = 0.f;
        sm.maxu = 0u; sm.r1 = 0u; sm.T = 0u;
        sm.nd = 0; sm.nt = 0;
        s_fastok = 0;
    }
    __syncthreads();
    const float q1x = sm.q[0], q1y = sm.q[1], q1z = sm.q[2];

    // ============ phase 1 fast path: certified survivor reuse (LDS coords) ============
    const bool attempt = (S0 >= G_SIZE) && (S0 <= CAP);
    if (attempt) {
        for (int j = tid; j < BINS; j += TPB) sm.hist[j] = 0u;
        for (int i = tid; i < S0; i += TPB) {
            unsigned uu = __float_as_uint(
                dist2f(sm.px[i], sm.py[i], sm.pz[i], q1x, q1y, q1z));
            sm.u[i] = uu;
            atomicMax(&sm.maxu, uu);
        }
        __syncthreads();
        unsigned maxu = sm.maxu;
        unsigned hb = (maxu == 0u) ? 0u : (32u - (unsigned)__clz(maxu));
        unsigned s3 = hb > 12u ? hb - 12u : 0u;
        for (int i = tid; i < S0; i += TPB) atomicAdd(&sm.hist[sm.u[i] >> s3], 1u);
        __syncthreads();
        unsigned T2 = find_bin(sm, G_SIZE, tid, lane, wid);
        const unsigned lo = T2 << s3;
        for (int i = tid; i < S0; i += TPB) {
            unsigned uu = sm.u[i];
            if (uu < lo) {
                int p = atomicAdd(&sm.nd, 1);
                if (p < G_SIZE) sm.sel[p] = i;
            } else if ((uu >> s3) == T2) {
                int p = atomicAdd(&sm.nt, 1);
                if (p < TIE_CAP) { sm.tu[p] = uu; sm.ti[p] = i; }
            }
        }
        __syncthreads();
        if (tid == 0) {
            int ok = 1;
            int nd = sm.nd; if (nd > G_SIZE) { nd = G_SIZE; ok = 0; }
            int need = G_SIZE - nd;
            if (sm.nt > TIE_CAP) ok = 0;
            int ec = sm.nt; if (ec > TIE_CAP) ec = TIE_CAP;
            if (need > ec) ok = 0;
            for (int a = 0; a < need && a < ec; ++a) {
                int best = a;
                for (int j = a + 1; j < ec; ++j)
                    if (sm.tu[j] < sm.tu[best] ||
                        (sm.tu[j] == sm.tu[best] && sm.idx[sm.ti[j]] < sm.idx[sm.ti[best]])) best = j;
                unsigned tub = sm.tu[best]; sm.tu[best] = sm.tu[a]; sm.tu[a] = tub;
                int tib = sm.ti[best]; sm.ti[best] = sm.ti[a]; sm.ti[a] = tib;
                sm.sel[nd + a] = sm.ti[a];
            }
            s_fastok = ok;
        }
        __syncthreads();
        if (s_fastok) {
            if (tid < G_SIZE) atomicMax(&sm.r1, sm.u[sm.sel[tid]]);
            __syncthreads();
            if (tid == 0) {
                // certificate: every non-survivor p has d0(p) >= R0 = sqrt(tau0),
                // so d1(p) >= R0 - delta; exact iff R0 - delta > r1 (fp margin)
                double R0 = sqrt((double)__uint_as_float(sm.tau0));
                double dl = sqrt((double)sm.delta2);
                double r1 = sqrt((double)__uint_as_float(sm.r1));
                if (!((R0 - dl) > r1 * 1.0001 + 1e-7)) s_fastok = 0;
            }
            __syncthreads();
        }
    }

    // ============ phase 1 fallback: exact full scan (rare) ============
    if (!attempt || !s_fastok) {
        knn_exact(P4, sm, q1x, q1y, q1z, tid, lane, wid, false);
    }

    // ============ mean / covariance over the exact 100 (LDS coords) ============
    float px = 0.f, py = 0.f, pz = 0.f;
    if (tid < G_SIZE) {
        int p = sm.sel[tid];
        px = sm.px[p]; py = sm.py[p]; pz = sm.pz[p];
        atomicAdd(&sm.acc[0], px);
        atomicAdd(&sm.acc[1], py);
        atomicAdd(&sm.acc[2], pz);
    }
    __syncthreads();
    float mx = sm.acc[0] * (1.0f / G_SIZE);
    float my = sm.acc[1] * (1.0f / G_SIZE);
    float mz = sm.acc[2] * (1.0f / G_SIZE);
    if (tid < G_SIZE) {
        float x = px - mx, y = py - my, z = pz - mz;
        atomicAdd(&sm.cov[0], x * x);
        atomicAdd(&sm.cov[1], x * y);
        atomicAdd(&sm.cov[2], x * z);
        atomicAdd(&sm.cov[3], y * y);
        atomicAdd(&sm.cov[4], y * z);
        atomicAdd(&sm.cov[5], z * z);
    }
    __syncthreads();
    if (tid < 6) covs[(size_t)gi * 6 + tid] = sm.cov[tid] * (1.0f / G_SIZE);

    // ============ last-block election (release-only; after ALL heavy work) ============
    __syncthreads();
    if (tid == 0) {
        unsigned old = __hip_atomic_fetch_add(&syncw[0], 1u, __ATOMIC_RELEASE,
                                              __HIP_MEMORY_SCOPE_AGENT);
        s_last = (old == (unsigned)(nblk - 1)) ? 1 : 0;
    }
    __syncthreads();
    if (!s_last) return;

    // ============ finalize (runs once, in the last block) ============
    // single acquire (one L2 invalidate, one block) to see all blocks' outputs
    (void)__hip_atomic_load(&syncw[0], __ATOMIC_ACQUIRE, __HIP_MEMORY_SCOPE_AGENT);
    const int NG = nblk;             // 240
    float et = 0.f;
    if (tid < NG) {
        float cf[6];
#pragma unroll
        for (int j = 0; j < 6; j++) cf[j] = covs[tid * 6 + j];
        double lam[3], dir[3];
        eig3(cf, lam, dir);
        double denom = lam[0] + lam[1] + lam[2] + 1e-9;
        et = (float)((lam[2] - lam[1]) / denom);
        sm.fin.dir[tid][0] = (float)dir[0];
        sm.fin.dir[tid][1] = (float)dir[1];
        sm.fin.dir[tid][2] = (float)dir[2];
        sm.fin.gm[tid][0] = gmeans[tid * 3 + 0];
        sm.fin.gm[tid][1] = gmeans[tid * 3 + 1];
        sm.fin.gm[tid][2] = gmeans[tid * 3 + 2];
    }
    __syncthreads();

    float st = 0.f;
    if (tid < NG) {
        int bb = tid / G_NUMS, gg0 = tid % G_NUMS;
        float gx = sm.fin.gm[tid][0], gy = sm.fin.gm[tid][1], gz = sm.fin.gm[tid][2];
        float bd = 3.4e38f; int bj = 0;
        for (int gg = 0; gg < G_NUMS; gg++) {
            if (gg == gg0) continue;
            int o = bb * G_NUMS + gg;
            float dx = gx - sm.fin.gm[o][0];
            float dy = gy - sm.fin.gm[o][1];
            float dz = gz - sm.fin.gm[o][2];
            float d = dx * dx + dy * dy + dz * dz;
            if (d < bd) { bd = d; bj = gg; }
        }
        int o = bb * G_NUMS + bj;
        float cosv = sm.fin.dir[tid][0] * sm.fin.dir[o][0] +
                     sm.fin.dir[tid][1] * sm.fin.dir[o][1] +
                     sm.fin.dir[tid][2] * sm.fin.dir[o][2];
        st = 1.f - cosv * cosv;
    }

    float e = et, s2v = st;
#pragma unroll
    for (int off = 32; off > 0; off >>= 1) {
        e += __shfl_down(e, off);
        s2v += __shfl_down(s2v, off);
    }
    if (lane == 0) { sm.fin.pe[wid] = e; sm.fin.ps[wid] = s2v; }
    __syncthreads();
    if (tid == 0) {
        float se = 0.f, ss = 0.f;
        for (int w = 0; w < NWAVES; w++) { se += sm.fin.pe[w]; ss += sm.fin.ps[w]; }
        out[0] = -se / (float)B + ss / (float)NG;
    }
}

extern "C" void kernel_launch(void* const* d_in, const int* in_sizes, int n_in,
                              void* d_out, int out_size, void* d_ws, size_t ws_size,
                              hipStream_t stream) {
    const float* pts = (const float*)d_in[0];
    float* out = (float*)d_out;
    float* ws = (float*)d_ws;
    int B = in_sizes[0] / (N_PTS * 3);   // 8
    int nblk = B * G_NUMS;               // 240

    float* gmeans = ws;                                  // 3*nblk floats
    float* covs = ws + (size_t)3 * nblk;                 // 6*nblk floats
    unsigned* syncw = (unsigned*)(ws + (size_t)9 * nblk);   // 16 u32

    hipMemsetAsync(syncw, 0, 64, stream);    // zero election counter

    fused_knn_kernel<<<dim3(nblk), dim3(TPB), 0, stream>>>(
        pts, gmeans, covs, out, syncw, B, nblk);
}